// Round 5
// baseline (466.144 us; speedup 1.0000x reference)
//
#include <hip/hip_runtime.h>
#include <stdint.h>

typedef __attribute__((ext_vector_type(8))) short bf16x8;
typedef __attribute__((ext_vector_type(4))) float f32x4;
typedef __attribute__((ext_vector_type(4))) unsigned int u32x4;

#define IMG 222

__device__ __forceinline__ unsigned short f2bf(float f){
  unsigned int u = __float_as_uint(f);
  return (unsigned short)((u + 0x7fffu + ((u >> 16) & 1u)) >> 16);
}

// HW packed f32->bf16 (RNE): lo -> D[15:0], hi -> D[31:16]
__device__ __forceinline__ unsigned int pk2bf(float lo, float hi){
  unsigned int r;
  asm("v_cvt_pk_bf16_f32 %0, %1, %2" : "=v"(r) : "v"(lo), "v"(hi));
  return r;
}

// XOR bank swizzles (ushort units). Involution: applied on write AND read.
__device__ __forceinline__ int sw128(int r, int c){ return r*128 + (c ^ ((r & 7) << 3)); }
__device__ __forceinline__ int sw64 (int r, int c){ return r*64  + (c ^ ((r & 7) << 3)); }

// Rebuild a v fragment (A-operand for O^T = V^T P~^T) from the producing
// layout: pkv[mi][p] = bf16 pair of v(ch = 32h + l15, tokens mi*16+lhi*4+2p,+1).
// Target: out[ks] lane(l15,lhi) = tokens ks*32+lhi*8+0..7 at same channel.
__device__ __forceinline__ void rebuild_bv(const unsigned int pkv[4][2], int l, bf16x8 out[2]){
  const int srcA = ((l & 16) << 1) + (l & 15);   // 32*(lhi&1) + l15
  #pragma unroll
  for (int ks = 0; ks < 2; ++ks){
    u32x4 wv;
    #pragma unroll
    for (int jj = 0; jj < 4; ++jj){
      const int src = srcA + ((jj >> 1) << 4);
      unsigned int va = (unsigned int)__shfl((int)pkv[2*ks][jj & 1], src);
      unsigned int vb = (unsigned int)__shfl((int)pkv[2*ks+1][jj & 1], src);
      wv[jj] = ((l >> 4) & 2) ? vb : va;
    }
    out[ks] = __builtin_bit_cast(bf16x8, wv);
  }
}

// Transpose + bf16-cast the weight matrices once per launch.
__global__ void prep_weights(const float* __restrict__ qkv_w,
                             const float* __restrict__ proj_w,
                             unsigned short* __restrict__ qwt,
                             unsigned short* __restrict__ pwt){
  int i = blockIdx.x * blockDim.x + threadIdx.x;
  if (i < 384*128){ int n = i >> 7, k = i & 127; qwt[i] = f2bf(qkv_w[k*384 + n]); }
  if (i < 128*128){ int n = i >> 7, k = i & 127; pwt[i] = f2bf(proj_w[k*384 - k*256 + n]); }
}
// NOTE: proj_w is [128][128]; expression k*384-k*256 == k*128 keeps one mul.

__global__ __launch_bounds__(256, 5)
void win_attn(const float* __restrict__ x,
              const float* __restrict__ qkv_b,
              const float* __restrict__ proj_b,
              const unsigned short* __restrict__ qwt,
              const unsigned short* __restrict__ pwt,
              float* __restrict__ out)
{
  // LDS 32KB (ushort units):
  //  r0 [0,8192)      : xs[64][128] -> q[64][128] -> P heads 0,1 -> osm[64][128]
  //  r1 [8192,16384)  : k[64][128]                -> P heads 2,3
  // v lives entirely in the producing wave's registers (pkv0, pkv1).
  extern __shared__ unsigned short lds[];
  unsigned short* r0 = lds;
  unsigned short* r1 = lds + 8192;

  const int tid = threadIdx.x;
  const int wid = tid >> 6;
  const int l   = tid & 63;
  const int l15 = l & 15;
  const int lhi = l >> 4;

  // XCD-aware block swizzle: 8192 blocks = 8 XCDs x 1024 contiguous windows.
  const int w  = (blockIdx.x & 7) * 1024 + (blockIdx.x >> 3);
  const int b  = w >> 10;
  const int wi = (w >> 5) & 31;
  const int wj = w & 31;

  // ---- phase 0: stage x window -> r0 (bf16, swizzled, b64-packed) ----
  {
    const int t  = tid >> 2;            // token 0..63
    const int cb = (tid & 3) * 32;      // channel base
    const int r  = t / 7, c = t - r*7;
    const int gh = wi*7 + r, gw = wj*7 + c;
    const bool valid = (t < 49) && (gh < IMG) && (gw < IMG);
    const float* src = x + (((size_t)((size_t)b*IMG + gh))*IMG + gw)*128 + cb;
    #pragma unroll
    for (int i = 0; i < 8; ++i){
      float4 v = valid ? *(const float4*)(src + i*4) : make_float4(0.f,0.f,0.f,0.f);
      uint2 pk; pk.x = pk2bf(v.x, v.y); pk.y = pk2bf(v.z, v.w);
      *(uint2*)(r0 + sw128(t, cb + i*4)) = pk;
    }
  }
  __syncthreads();

  // ---- load x A/B fragments into registers, then free r0 for q ----
  bf16x8 a[4][4];
  #pragma unroll
  for (int mi = 0; mi < 4; ++mi)
    #pragma unroll
    for (int ks = 0; ks < 4; ++ks)
      a[mi][ks] = *(const bf16x8*)(r0 + sw128(mi*16 + l15, ks*32 + lhi*8));
  __syncthreads();

  const float scale = 0.17677669529663687f;   // 32^-0.5

  // ---- phase 1a: q,k tiles (swapped mfma: col=token, regs=4 consecutive ch) ----
  #pragma unroll
  for (int s = 0; s < 4; ++s){
    const int nt = wid + s*4;               // tiles 0..15: q (nt<8), k (nt>=8)
    bf16x8 bfr[4];
    #pragma unroll
    for (int ks = 0; ks < 4; ++ks)
      bfr[ks] = *(const bf16x8*)(qwt + (nt*16 + l15)*128 + ks*32 + lhi*8);
    const float4 bias4 = *(const float4*)(qkv_b + nt*16 + lhi*4);
    __builtin_amdgcn_s_setprio(1);
    #pragma unroll
    for (int mi = 0; mi < 4; ++mi){
      f32x4 acc = {0.f,0.f,0.f,0.f};
      #pragma unroll
      for (int ks = 0; ks < 4; ++ks)
        acc = __builtin_amdgcn_mfma_f32_16x16x32_bf16(bfr[ks], a[mi][ks], acc, 0, 0, 0);
      uint2 pk;
      if (s < 2){
        pk.x = pk2bf((acc[0]+bias4.x)*scale, (acc[1]+bias4.y)*scale);
        pk.y = pk2bf((acc[2]+bias4.z)*scale, (acc[3]+bias4.w)*scale);
        *(uint2*)(r0 + sw128(mi*16 + l15, nt*16 + lhi*4)) = pk;
      } else {
        pk.x = pk2bf(acc[0]+bias4.x, acc[1]+bias4.y);
        pk.y = pk2bf(acc[2]+bias4.z, acc[3]+bias4.w);
        *(uint2*)(r1 + sw128(mi*16 + l15, (nt-8)*16 + lhi*4)) = pk;
      }
    }
    __builtin_amdgcn_s_setprio(0);
  }

  // ---- phase 1b: v tiles for OWN head (normal mfma: col=ch, regs=4 tokens) ----
  unsigned int pkv0[4][2], pkv1[4][2];       // v of head wid, all 32 ch, packed bf16
  {
    const int nt0 = 16 + 2*wid;              // ch 32h .. 32h+15
    bf16x8 bfr[4];
    #pragma unroll
    for (int ks = 0; ks < 4; ++ks)
      bfr[ks] = *(const bf16x8*)(qwt + (nt0*16 + l15)*128 + ks*32 + lhi*8);
    const float bias = qkv_b[nt0*16 + l15];
    __builtin_amdgcn_s_setprio(1);
    #pragma unroll
    for (int mi = 0; mi < 4; ++mi){
      f32x4 acc = {0.f,0.f,0.f,0.f};
      #pragma unroll
      for (int ks = 0; ks < 4; ++ks)
        acc = __builtin_amdgcn_mfma_f32_16x16x32_bf16(a[mi][ks], bfr[ks], acc, 0, 0, 0);
      pkv0[mi][0] = pk2bf(acc[0]+bias, acc[1]+bias);   // tokens mi*16+lhi*4 +0,+1
      pkv0[mi][1] = pk2bf(acc[2]+bias, acc[3]+bias);   // tokens +2,+3
    }
    __builtin_amdgcn_s_setprio(0);
  }
  {
    const int nt1 = 17 + 2*wid;              // ch 32h+16 .. 32h+31
    bf16x8 bfr[4];
    #pragma unroll
    for (int ks = 0; ks < 4; ++ks)
      bfr[ks] = *(const bf16x8*)(qwt + (nt1*16 + l15)*128 + ks*32 + lhi*8);
    const float bias = qkv_b[nt1*16 + l15];
    __builtin_amdgcn_s_setprio(1);
    #pragma unroll
    for (int mi = 0; mi < 4; ++mi){
      f32x4 acc = {0.f,0.f,0.f,0.f};
      #pragma unroll
      for (int ks = 0; ks < 4; ++ks)
        acc = __builtin_amdgcn_mfma_f32_16x16x32_bf16(a[mi][ks], bfr[ks], acc, 0, 0, 0);
      pkv1[mi][0] = pk2bf(acc[0]+bias, acc[1]+bias);
      pkv1[mi][1] = pk2bf(acc[2]+bias, acc[3]+bias);
    }
    __builtin_amdgcn_s_setprio(0);
  }
  __syncthreads();

  // ---- phase 2: S^T = K·Q^T per head (wave = head), softmax over k ----
  const int h = wid;
  unsigned short* ph = lds + h*4096;          // this head's P~ [64 q][64 k] (swizzled)
  bf16x8 aq[4], bk[4];
  #pragma unroll
  for (int i = 0; i < 4; ++i){
    aq[i] = *(const bf16x8*)(r0 + sw128(i*16 + l15, h*32 + lhi*8));
    bk[i] = *(const bf16x8*)(r1 + sw128(i*16 + l15, h*32 + lhi*8));
  }
  __syncthreads();   // all q/k reads done; r0+r1 become P~ regions

  float invs[4];
  #pragma unroll
  for (int mi = 0; mi < 4; ++mi){
    // S^T tile: col=l15=q-token (mi*16+l15), row=k = ni*16 + lhi*4 + r
    f32x4 st[4];
    __builtin_amdgcn_s_setprio(1);
    #pragma unroll
    for (int ni = 0; ni < 4; ++ni){
      f32x4 z = {0.f,0.f,0.f,0.f};
      st[ni] = __builtin_amdgcn_mfma_f32_16x16x32_bf16(bk[ni], aq[mi], z, 0, 0, 0);
    }
    __builtin_amdgcn_s_setprio(0);
    // mask k >= 49 (ni==3: k = 48 + lhi*4 + r; only lhi==0,r==0 valid)
    st[3][1] = -1e30f; st[3][2] = -1e30f; st[3][3] = -1e30f;
    if (lhi != 0) st[3][0] = -1e30f;
    float m = st[0][0];
    #pragma unroll
    for (int ni = 0; ni < 4; ++ni)
      #pragma unroll
      for (int r = 0; r < 4; ++r)
        m = fmaxf(m, st[ni][r]);
    m = fmaxf(m, __shfl_xor(m, 16));
    m = fmaxf(m, __shfl_xor(m, 32));
    float e[4][4], s = 0.f;
    #pragma unroll
    for (int ni = 0; ni < 4; ++ni)
      #pragma unroll
      for (int r = 0; r < 4; ++r){
        e[ni][r] = __expf(st[ni][r] - m);
        s += e[ni][r];
      }
    s += __shfl_xor(s, 16);
    s += __shfl_xor(s, 32);
    invs[mi] = __builtin_amdgcn_rcpf(s);      // normalize deferred to O
    #pragma unroll
    for (int ni = 0; ni < 4; ++ni){
      uint2 pk;
      pk.x = pk2bf(e[ni][0], e[ni][1]);
      pk.y = pk2bf(e[ni][2], e[ni][3]);
      *(uint2*)(ph + sw64(mi*16 + l15, ni*16 + lhi*4)) = pk;
    }
  }

  // ---- phase 3 prep: load P fragments; rebuild v fragments from registers ----
  bf16x8 pa[4][2];
  #pragma unroll
  for (int mi = 0; mi < 4; ++mi)
    #pragma unroll
    for (int ks = 0; ks < 2; ++ks)
      pa[mi][ks] = *(const bf16x8*)(ph + sw64(mi*16 + l15, ks*32 + lhi*8));
  bf16x8 bv0[2], bv1[2];
  rebuild_bv(pkv0, l, bv0);
  rebuild_bv(pkv1, l, bv1);
  __syncthreads();   // P reads done; r0 becomes osm [64 tok][128 ch]

  // ---- phase 3: O^T = V^T · P~^T  (swapped mfma) ----
  #pragma unroll
  for (int mi = 0; mi < 4; ++mi){
    const float is = invs[mi];
    __builtin_amdgcn_s_setprio(1);
    f32x4 acc0 = {0.f,0.f,0.f,0.f}, acc1 = {0.f,0.f,0.f,0.f};
    acc0 = __builtin_amdgcn_mfma_f32_16x16x32_bf16(bv0[0], pa[mi][0], acc0, 0, 0, 0);
    acc0 = __builtin_amdgcn_mfma_f32_16x16x32_bf16(bv0[1], pa[mi][1], acc0, 0, 0, 0);
    acc1 = __builtin_amdgcn_mfma_f32_16x16x32_bf16(bv1[0], pa[mi][0], acc1, 0, 0, 0);
    acc1 = __builtin_amdgcn_mfma_f32_16x16x32_bf16(bv1[1], pa[mi][1], acc1, 0, 0, 0);
    __builtin_amdgcn_s_setprio(0);
    uint2 pk0, pk1;
    pk0.x = pk2bf(acc0[0]*is, acc0[1]*is);
    pk0.y = pk2bf(acc0[2]*is, acc0[3]*is);
    pk1.x = pk2bf(acc1[0]*is, acc1[1]*is);
    pk1.y = pk2bf(acc1[2]*is, acc1[3]*is);
    *(uint2*)(r0 + sw128(mi*16 + l15, h*32 + lhi*4))      = pk0;
    *(uint2*)(r0 + sw128(mi*16 + l15, h*32 + 16 + lhi*4)) = pk1;
  }
  __syncthreads();

  // ---- phase 4: proj GEMM (swapped) + bias + float4 scatter ----
  bf16x8 ao[4][4];
  #pragma unroll
  for (int mi = 0; mi < 4; ++mi)
    #pragma unroll
    for (int ks = 0; ks < 4; ++ks)
      ao[mi][ks] = *(const bf16x8*)(r0 + sw128(mi*16 + l15, ks*32 + lhi*8));

  #pragma unroll
  for (int nj = 0; nj < 2; ++nj){
    const int ni = wid + nj*4;               // out-channel tile 0..7
    bf16x8 pbw[4];
    #pragma unroll
    for (int ks = 0; ks < 4; ++ks)
      pbw[ks] = *(const bf16x8*)(pwt + (ni*16 + l15)*128 + ks*32 + lhi*8);
    const float4 bias4 = *(const float4*)(proj_b + ni*16 + lhi*4);
    #pragma unroll
    for (int mi = 0; mi < 4; ++mi){
      __builtin_amdgcn_s_setprio(1);
      f32x4 acc = {0.f,0.f,0.f,0.f};
      #pragma unroll
      for (int ks = 0; ks < 4; ++ks)
        acc = __builtin_amdgcn_mfma_f32_16x16x32_bf16(pbw[ks], ao[mi][ks], acc, 0, 0, 0);
      __builtin_amdgcn_s_setprio(0);
      const int t = mi*16 + l15;             // token (per-lane uniform across regs)
      if (t < 49){
        const int rr = t / 7, cc = t - rr*7;
        const int gh = wi*7 + rr, gw = wj*7 + cc;
        if (gh < IMG && gw < IMG){
          float4 o = make_float4(acc[0]+bias4.x, acc[1]+bias4.y,
                                 acc[2]+bias4.z, acc[3]+bias4.w);
          *(float4*)(out + (((size_t)((size_t)b*IMG + gh))*IMG + gw)*128 + ni*16 + lhi*4) = o;
        }
      }
    }
  }
}

extern "C" void kernel_launch(void* const* d_in, const int* in_sizes, int n_in,
                              void* d_out, int out_size, void* d_ws, size_t ws_size,
                              hipStream_t stream) {
  const float* x      = (const float*)d_in[0];
  const float* qkv_w  = (const float*)d_in[1];
  const float* qkv_b  = (const float*)d_in[2];
  const float* proj_w = (const float*)d_in[3];
  const float* proj_b = (const float*)d_in[4];
  float* out = (float*)d_out;

  unsigned short* qwt = (unsigned short*)d_ws;          // 384*128 bf16
  unsigned short* pwt = qwt + 384*128;                  // 128*128 bf16

  hipLaunchKernelGGL(prep_weights, dim3(192), dim3(256), 0, stream,
                     qkv_w, proj_w, qwt, pwt);
  hipLaunchKernelGGL(win_attn, dim3(8192), dim3(256), 32768, stream,
                     x, qkv_b, proj_b, qwt, pwt, out);
}

// Round 6
// 207.604 us; speedup vs baseline: 2.2454x; 2.2454x over previous
//
#include <hip/hip_runtime.h>
#include <stdint.h>

typedef __attribute__((ext_vector_type(8))) short bf16x8;
typedef __attribute__((ext_vector_type(4))) float f32x4;
typedef __attribute__((ext_vector_type(4))) unsigned int u32x4;

#define IMG 222

__device__ __forceinline__ unsigned short f2bf(float f){
  unsigned int u = __float_as_uint(f);
  return (unsigned short)((u + 0x7fffu + ((u >> 16) & 1u)) >> 16);
}

// HW packed f32->bf16 (RNE): lo -> D[15:0], hi -> D[31:16]
__device__ __forceinline__ unsigned int pk2bf(float lo, float hi){
  unsigned int r;
  asm("v_cvt_pk_bf16_f32 %0, %1, %2" : "=v"(r) : "v"(lo), "v"(hi));
  return r;
}

// XOR bank swizzles (ushort units). Involution: applied on write AND read.
__device__ __forceinline__ int sw128(int r, int c){ return r*128 + (c ^ ((r & 7) << 3)); }
__device__ __forceinline__ int sw64 (int r, int c){ return r*64  + (c ^ ((r & 7) << 3)); }

// Rebuild a v fragment (A-operand for O^T = V^T P~^T) from the producing
// layout: pkv[mi][p] = bf16 pair of v(ch = 32h + l15, tokens mi*16+lhi*4+2p,+1).
// Target: out[ks] lane(l15,lhi) = tokens ks*32+lhi*8+0..7 at same channel.
// src0/src1 are precomputed shfl source lanes (shared across all rebuilds).
__device__ __forceinline__ void rebuild_bv(const unsigned int pkv[4][2], int src0, int src1,
                                           bool hiSel, bf16x8 out[2]){
  #pragma unroll
  for (int ks = 0; ks < 2; ++ks){
    u32x4 wv;
    #pragma unroll
    for (int jj = 0; jj < 4; ++jj){
      const int src = (jj >> 1) ? src1 : src0;
      unsigned int va = (unsigned int)__shfl((int)pkv[2*ks][jj & 1], src);
      unsigned int vb = (unsigned int)__shfl((int)pkv[2*ks+1][jj & 1], src);
      wv[jj] = hiSel ? vb : va;
    }
    out[ks] = __builtin_bit_cast(bf16x8, wv);
  }
}

// Transpose + bf16-cast the weight matrices once per launch.
__global__ void prep_weights(const float* __restrict__ qkv_w,
                             const float* __restrict__ proj_w,
                             unsigned short* __restrict__ qwt,
                             unsigned short* __restrict__ pwt){
  int i = blockIdx.x * blockDim.x + threadIdx.x;
  if (i < 384*128){ int n = i >> 7, k = i & 127; qwt[i] = f2bf(qkv_w[k*384 + n]); }
  if (i < 128*128){ int n = i >> 7, k = i & 127; pwt[i] = f2bf(proj_w[k*128 + n]); }
}

__global__ __launch_bounds__(256, 4)
void win_attn(const float* __restrict__ x,
              const float* __restrict__ qkv_b,
              const float* __restrict__ proj_b,
              const unsigned short* __restrict__ qwt,
              const unsigned short* __restrict__ pwt,
              float* __restrict__ out)
{
  // LDS 32KB (ushort units):
  //  r0 [0,8192)      : xs[64][128] -> q[64][128] -> P heads 0,1 -> osm[64][128]
  //  r1 [8192,16384)  : k[64][128]                -> P heads 2,3
  // v lives entirely in the producing wave's registers (pkv0, pkv1).
  extern __shared__ unsigned short lds[];
  unsigned short* r0 = lds;
  unsigned short* r1 = lds + 8192;

  const int tid = threadIdx.x;
  const int wid = tid >> 6;
  const int l   = tid & 63;
  const int l15 = l & 15;
  const int lhi = l >> 4;

  // Shared shfl source lanes for all register rebuilds:
  //   src0 = l15 + 32*(lhi&1), src1 = src0 + 16; select hi by lhi bit1.
  const int src0 = ((l & 16) << 1) + l15;
  const int src1 = src0 + 16;
  const bool hiSel = (l & 32) != 0;

  // XCD-aware block swizzle: 8192 blocks = 8 XCDs x 1024 contiguous windows.
  const int w  = (blockIdx.x & 7) * 1024 + (blockIdx.x >> 3);
  const int b  = w >> 10;
  const int wi = (w >> 5) & 31;
  const int wj = w & 31;

  // ---- phase 0: stage x window -> r0 (bf16, swizzled, b64-packed) ----
  {
    const int t  = tid >> 2;            // token 0..63
    const int cb = (tid & 3) * 32;      // channel base
    const int r  = t / 7, c = t - r*7;
    const int gh = wi*7 + r, gw = wj*7 + c;
    const bool valid = (t < 49) && (gh < IMG) && (gw < IMG);
    const float* src = x + (((size_t)((size_t)b*IMG + gh))*IMG + gw)*128 + cb;
    #pragma unroll
    for (int i = 0; i < 8; ++i){
      float4 v = valid ? *(const float4*)(src + i*4) : make_float4(0.f,0.f,0.f,0.f);
      uint2 pk; pk.x = pk2bf(v.x, v.y); pk.y = pk2bf(v.z, v.w);
      *(uint2*)(r0 + sw128(t, cb + i*4)) = pk;
    }
  }
  __syncthreads();

  // ---- load x A/B fragments into registers, then free r0 for q ----
  bf16x8 a[4][4];
  #pragma unroll
  for (int mi = 0; mi < 4; ++mi)
    #pragma unroll
    for (int ks = 0; ks < 4; ++ks)
      a[mi][ks] = *(const bf16x8*)(r0 + sw128(mi*16 + l15, ks*32 + lhi*8));
  __syncthreads();

  const float scale = 0.17677669529663687f;   // 32^-0.5

  // ---- phase 1a: q,k tiles (swapped mfma: col=token, regs=4 consecutive ch) ----
  #pragma unroll
  for (int s = 0; s < 4; ++s){
    const int nt = wid + s*4;               // tiles 0..15: q (nt<8), k (nt>=8)
    bf16x8 bfr[4];
    #pragma unroll
    for (int ks = 0; ks < 4; ++ks)
      bfr[ks] = *(const bf16x8*)(qwt + (nt*16 + l15)*128 + ks*32 + lhi*8);
    const float4 bias4 = *(const float4*)(qkv_b + nt*16 + lhi*4);
    __builtin_amdgcn_s_setprio(1);
    #pragma unroll
    for (int mi = 0; mi < 4; ++mi){
      f32x4 acc = {0.f,0.f,0.f,0.f};
      #pragma unroll
      for (int ks = 0; ks < 4; ++ks)
        acc = __builtin_amdgcn_mfma_f32_16x16x32_bf16(bfr[ks], a[mi][ks], acc, 0, 0, 0);
      uint2 pk;
      if (s < 2){
        pk.x = pk2bf((acc[0]+bias4.x)*scale, (acc[1]+bias4.y)*scale);
        pk.y = pk2bf((acc[2]+bias4.z)*scale, (acc[3]+bias4.w)*scale);
        *(uint2*)(r0 + sw128(mi*16 + l15, nt*16 + lhi*4)) = pk;
      } else {
        pk.x = pk2bf(acc[0]+bias4.x, acc[1]+bias4.y);
        pk.y = pk2bf(acc[2]+bias4.z, acc[3]+bias4.w);
        *(uint2*)(r1 + sw128(mi*16 + l15, (nt-8)*16 + lhi*4)) = pk;
      }
    }
    __builtin_amdgcn_s_setprio(0);
  }

  // ---- phase 1b: v tiles for OWN head (normal mfma: col=ch, regs=4 tokens) ----
  unsigned int pkv0[4][2], pkv1[4][2];       // v of head wid, all 32 ch, packed bf16
  {
    const int nt0 = 16 + 2*wid;              // ch 32h .. 32h+15
    bf16x8 bfr[4];
    #pragma unroll
    for (int ks = 0; ks < 4; ++ks)
      bfr[ks] = *(const bf16x8*)(qwt + (nt0*16 + l15)*128 + ks*32 + lhi*8);
    const float bias = qkv_b[nt0*16 + l15];
    __builtin_amdgcn_s_setprio(1);
    #pragma unroll
    for (int mi = 0; mi < 4; ++mi){
      f32x4 acc = {0.f,0.f,0.f,0.f};
      #pragma unroll
      for (int ks = 0; ks < 4; ++ks)
        acc = __builtin_amdgcn_mfma_f32_16x16x32_bf16(a[mi][ks], bfr[ks], acc, 0, 0, 0);
      pkv0[mi][0] = pk2bf(acc[0]+bias, acc[1]+bias);   // tokens mi*16+lhi*4 +0,+1
      pkv0[mi][1] = pk2bf(acc[2]+bias, acc[3]+bias);   // tokens +2,+3
    }
    __builtin_amdgcn_s_setprio(0);
  }
  {
    const int nt1 = 17 + 2*wid;              // ch 32h+16 .. 32h+31
    bf16x8 bfr[4];
    #pragma unroll
    for (int ks = 0; ks < 4; ++ks)
      bfr[ks] = *(const bf16x8*)(qwt + (nt1*16 + l15)*128 + ks*32 + lhi*8);
    const float bias = qkv_b[nt1*16 + l15];
    __builtin_amdgcn_s_setprio(1);
    #pragma unroll
    for (int mi = 0; mi < 4; ++mi){
      f32x4 acc = {0.f,0.f,0.f,0.f};
      #pragma unroll
      for (int ks = 0; ks < 4; ++ks)
        acc = __builtin_amdgcn_mfma_f32_16x16x32_bf16(a[mi][ks], bfr[ks], acc, 0, 0, 0);
      pkv1[mi][0] = pk2bf(acc[0]+bias, acc[1]+bias);
      pkv1[mi][1] = pk2bf(acc[2]+bias, acc[3]+bias);
    }
    __builtin_amdgcn_s_setprio(0);
  }
  __syncthreads();

  // ---- phase 2: S^T = K·Q^T per head (wave = head), softmax over k ----
  const int h = wid;
  unsigned short* ph = lds + h*4096;          // this head's P~ [64 q][64 k] (swizzled)
  bf16x8 aq[4], bk[4];
  #pragma unroll
  for (int i = 0; i < 4; ++i){
    aq[i] = *(const bf16x8*)(r0 + sw128(i*16 + l15, h*32 + lhi*8));
    bk[i] = *(const bf16x8*)(r1 + sw128(i*16 + l15, h*32 + lhi*8));
  }
  __syncthreads();   // all q/k reads done; r0+r1 become P~ regions

  float invs[4];
  #pragma unroll
  for (int mi = 0; mi < 4; ++mi){
    // S^T tile: col=l15=q-token (mi*16+l15), row=k = ni*16 + lhi*4 + r
    f32x4 st[4];
    __builtin_amdgcn_s_setprio(1);
    #pragma unroll
    for (int ni = 0; ni < 4; ++ni){
      f32x4 z = {0.f,0.f,0.f,0.f};
      st[ni] = __builtin_amdgcn_mfma_f32_16x16x32_bf16(bk[ni], aq[mi], z, 0, 0, 0);
    }
    __builtin_amdgcn_s_setprio(0);
    // mask k >= 49 (ni==3: k = 48 + lhi*4 + r; only lhi==0,r==0 valid)
    st[3][1] = -1e30f; st[3][2] = -1e30f; st[3][3] = -1e30f;
    if (lhi != 0) st[3][0] = -1e30f;
    float m = st[0][0];
    #pragma unroll
    for (int ni = 0; ni < 4; ++ni)
      #pragma unroll
      for (int r = 0; r < 4; ++r)
        m = fmaxf(m, st[ni][r]);
    m = fmaxf(m, __shfl_xor(m, 16));
    m = fmaxf(m, __shfl_xor(m, 32));
    float e[4][4], s = 0.f;
    #pragma unroll
    for (int ni = 0; ni < 4; ++ni)
      #pragma unroll
      for (int r = 0; r < 4; ++r){
        e[ni][r] = __expf(st[ni][r] - m);
        s += e[ni][r];
      }
    s += __shfl_xor(s, 16);
    s += __shfl_xor(s, 32);
    invs[mi] = __builtin_amdgcn_rcpf(s);      // normalize deferred to O
    #pragma unroll
    for (int ni = 0; ni < 4; ++ni){
      uint2 pk;
      pk.x = pk2bf(e[ni][0], e[ni][1]);
      pk.y = pk2bf(e[ni][2], e[ni][3]);
      *(uint2*)(ph + sw64(mi*16 + l15, ni*16 + lhi*4)) = pk;
    }
  }

  // ---- phase 3 prep: load P fragments; rebuild v fragments from registers ----
  bf16x8 pa[4][2];
  #pragma unroll
  for (int mi = 0; mi < 4; ++mi)
    #pragma unroll
    for (int ks = 0; ks < 2; ++ks)
      pa[mi][ks] = *(const bf16x8*)(ph + sw64(mi*16 + l15, ks*32 + lhi*8));
  bf16x8 bv0[2], bv1[2];
  rebuild_bv(pkv0, src0, src1, hiSel, bv0);
  rebuild_bv(pkv1, src0, src1, hiSel, bv1);
  __syncthreads();   // P reads done; r0 becomes osm [64 tok][128 ch]

  // ---- phase 3: O^T = V^T · P~^T  (swapped mfma) ----
  #pragma unroll
  for (int mi = 0; mi < 4; ++mi){
    const float is = invs[mi];
    __builtin_amdgcn_s_setprio(1);
    f32x4 acc0 = {0.f,0.f,0.f,0.f}, acc1 = {0.f,0.f,0.f,0.f};
    acc0 = __builtin_amdgcn_mfma_f32_16x16x32_bf16(bv0[0], pa[mi][0], acc0, 0, 0, 0);
    acc0 = __builtin_amdgcn_mfma_f32_16x16x32_bf16(bv0[1], pa[mi][1], acc0, 0, 0, 0);
    acc1 = __builtin_amdgcn_mfma_f32_16x16x32_bf16(bv1[0], pa[mi][0], acc1, 0, 0, 0);
    acc1 = __builtin_amdgcn_mfma_f32_16x16x32_bf16(bv1[1], pa[mi][1], acc1, 0, 0, 0);
    __builtin_amdgcn_s_setprio(0);
    uint2 pk0, pk1;
    pk0.x = pk2bf(acc0[0]*is, acc0[1]*is);
    pk0.y = pk2bf(acc0[2]*is, acc0[3]*is);
    pk1.x = pk2bf(acc1[0]*is, acc1[1]*is);
    pk1.y = pk2bf(acc1[2]*is, acc1[3]*is);
    *(uint2*)(r0 + sw128(mi*16 + l15, h*32 + lhi*4))      = pk0;
    *(uint2*)(r0 + sw128(mi*16 + l15, h*32 + 16 + lhi*4)) = pk1;
  }
  __syncthreads();

  // ---- phase 4: proj GEMM (swapped) + bias + float4 scatter ----
  bf16x8 ao[4][4];
  #pragma unroll
  for (int mi = 0; mi < 4; ++mi)
    #pragma unroll
    for (int ks = 0; ks < 4; ++ks)
      ao[mi][ks] = *(const bf16x8*)(r0 + sw128(mi*16 + l15, ks*32 + lhi*8));

  #pragma unroll
  for (int nj = 0; nj < 2; ++nj){
    const int ni = wid + nj*4;               // out-channel tile 0..7
    bf16x8 pbw[4];
    #pragma unroll
    for (int ks = 0; ks < 4; ++ks)
      pbw[ks] = *(const bf16x8*)(pwt + (ni*16 + l15)*128 + ks*32 + lhi*8);
    const float4 bias4 = *(const float4*)(proj_b + ni*16 + lhi*4);
    #pragma unroll
    for (int mi = 0; mi < 4; ++mi){
      __builtin_amdgcn_s_setprio(1);
      f32x4 acc = {0.f,0.f,0.f,0.f};
      #pragma unroll
      for (int ks = 0; ks < 4; ++ks)
        acc = __builtin_amdgcn_mfma_f32_16x16x32_bf16(pbw[ks], ao[mi][ks], acc, 0, 0, 0);
      __builtin_amdgcn_s_setprio(0);
      const int t = mi*16 + l15;             // token (per-lane uniform across regs)
      if (t < 49){
        const int rr = t / 7, cc = t - rr*7;
        const int gh = wi*7 + rr, gw = wj*7 + cc;
        if (gh < IMG && gw < IMG){
          float4 o = make_float4(acc[0]+bias4.x, acc[1]+bias4.y,
                                 acc[2]+bias4.z, acc[3]+bias4.w);
          *(float4*)(out + (((size_t)((size_t)b*IMG + gh))*IMG + gw)*128 + ni*16 + lhi*4) = o;
        }
      }
    }
  }
}

extern "C" void kernel_launch(void* const* d_in, const int* in_sizes, int n_in,
                              void* d_out, int out_size, void* d_ws, size_t ws_size,
                              hipStream_t stream) {
  const float* x      = (const float*)d_in[0];
  const float* qkv_w  = (const float*)d_in[1];
  const float* qkv_b  = (const float*)d_in[2];
  const float* proj_w = (const float*)d_in[3];
  const float* proj_b = (const float*)d_in[4];
  float* out = (float*)d_out;

  unsigned short* qwt = (unsigned short*)d_ws;          // 384*128 bf16
  unsigned short* pwt = qwt + 384*128;                  // 128*128 bf16

  hipLaunchKernelGGL(prep_weights, dim3(192), dim3(256), 0, stream,
                     qkv_w, proj_w, qwt, pwt);
  hipLaunchKernelGGL(win_attn, dim3(8192), dim3(256), 32768, stream,
                     x, qkv_b, proj_b, qwt, pwt, out);
}